// Round 11
// baseline (700.299 us; speedup 1.0000x reference)
//
#include <hip/hip_runtime.h>
#include <cstddef>
#include <cstdint>

// ---------------- problem constants ----------------
constexpr int B_    = 128;
constexpr int NQ_   = 32;
constexpr int NC_   = 40;
constexpr int NMAX_ = 40;
constexpr int EQ_   = 160;
constexpr int EC_   = 240;
constexpr int EMAX_ = 256;
constexpr int D_    = 128;
constexpr int TD_   = 16;
constexpr int NPROP_ = 5;
constexpr int ITERS_ = 20;
constexpr float TEMP_ = 0.1f;
constexpr int NF_   = 32;
constexpr int EF_   = 16;
constexpr int NPB_  = NQ_ + NC_;   // 72 nodes / batch
constexpr int EPB_  = EQ_ + EC_;   // 400 edges / batch
constexpr int NTOT_ = B_ * NPB_;   // 9216
constexpr int ETOT_ = B_ * EPB_;   // 51200
constexpr int DEGCAP_ = 64;
constexpr float L2E10_ = 14.4269504088896f;  // 10 * log2(e)

typedef _Float16 f16x8 __attribute__((ext_vector_type(8)));
typedef _Float16 f16x4 __attribute__((ext_vector_type(4)));
typedef float f32x4 __attribute__((ext_vector_type(4)));

__device__ __forceinline__ void gload16(const void* g, void* l) {
  __builtin_amdgcn_global_load_lds(
      (const __attribute__((address_space(1))) unsigned int*)g,
      (__attribute__((address_space(3))) unsigned int*)l, 16, 0, 0);
}
__device__ __forceinline__ float ex2(float x) { return __builtin_amdgcn_exp2f(x); }
__device__ __forceinline__ float lg2(float x) { return __builtin_amdgcn_logf(x); }

// ---------------- index building ----------------
__global__ __launch_bounds__(256) void k_build_idx(
    const int* __restrict__ fq, const int* __restrict__ tq,
    const int* __restrict__ fc, const int* __restrict__ tc,
    int* __restrict__ from_idx, int* __restrict__ to_idx)
{
  int i = blockIdx.x * blockDim.x + threadIdx.x;
  if (i >= ETOT_) return;
  int b = i / EPB_, j = i - b * EPB_;
  int f, t;
  if (j < EQ_) {
    f = fq[b*EQ_ + j] + b*NPB_;
    t = tq[b*EQ_ + j] + b*NPB_;
  } else {
    int jj = j - EQ_;
    f = fc[b*EC_ + jj] + b*NPB_ + NQ_;
    t = tc[b*EC_ + jj] + b*NPB_ + NQ_;
  }
  from_idx[i] = f;
  to_idx[i]   = t;
}

// ---------------- per-node edge lists (deterministic ascending order) ----------------
__global__ __launch_bounds__(256) void k_build_lists(
    const int* __restrict__ fq, const int* __restrict__ tq,
    const int* __restrict__ fc, const int* __restrict__ tc,
    int* __restrict__ in_cnt, int* __restrict__ in_list,
    int* __restrict__ out_cnt, int* __restrict__ out_list)
{
  const int b = blockIdx.x, tid = threadIdx.x;
  __shared__ short sf[EPB_], st[EPB_];
  for (int j = tid; j < EPB_; j += 256) {
    int f, t;
    if (j < EQ_) { f = fq[b*EQ_ + j];              t = tq[b*EQ_ + j]; }
    else         { f = fc[b*EC_ + (j-EQ_)] + NQ_;  t = tc[b*EC_ + (j-EQ_)] + NQ_; }
    sf[j] = (short)f; st[j] = (short)t;
  }
  __syncthreads();
  if (tid < NPB_) {
    const int g = b*NPB_ + tid;
    int ic = 0, oc = 0;
    for (int j = 0; j < EPB_; ++j) {
      if ((int)st[j] == tid && ic < DEGCAP_) in_list[g*DEGCAP_ + (ic++)] = j;
      if ((int)sf[j] == tid && oc < DEGCAP_) out_list[g*DEGCAP_ + (oc++)] = j;
    }
    in_cnt[g] = ic; out_cnt[g] = oc;
  }
}

// ---------------- weight prep: W1Tn, W1Te, bcat1 ----------------
__global__ __launch_bounds__(256) void k_prep_w(
    const float* __restrict__ Wm1, const float* __restrict__ Wr1,
    const float* __restrict__ bm1, const float* __restrict__ br1,
    _Float16* __restrict__ W1Tn, _Float16* __restrict__ W1Te,
    float* __restrict__ bcat1)
{
  int i = blockIdx.x * 256 + threadIdx.x;
  if (i < 1024*128) {
    int n = i >> 7, k = i & 127;
    float v;
    if (n < 512) {            // F-part: W1 row k
      v = (n < 256) ? Wm1[(size_t)k*256 + n]
                    : Wr1[(size_t)(k + 128)*256 + (n - 256)];
    } else {                  // T-part: W1 row 128+k
      int n2 = n - 512;
      v = (n2 < 256) ? Wm1[(size_t)(128 + k)*256 + n2]
                     : Wr1[(size_t)k*256 + (n2 - 256)];
    }
    W1Tn[i] = (_Float16)v;
  }
  int j = i - 1024*128;
  if (j >= 0 && j < 512*128) {
    int n = j >> 7, k = j & 127;   // W1 row 256+k
    float v = (n < 256) ? Wm1[(size_t)(256 + k)*256 + n]
                        : Wr1[(size_t)(256 + k)*256 + (n - 256)];
    W1Te[j] = (_Float16)v;
  }
  if (i < 512) bcat1[i] = (i < 256) ? bm1[i] : br1[i - 256];
}

// ---------------- fused update-weight prep ----------------
__global__ __launch_bounds__(256) void k_prep_wu(
    const float* __restrict__ Wm2, const float* __restrict__ Wr2,
    const float* __restrict__ Wu,
    const float* __restrict__ bm2, const float* __restrict__ br2,
    _Float16* __restrict__ WuT, float* __restrict__ c1, float* __restrict__ c2)
{
  int i = blockIdx.x * 256 + threadIdx.x;
  if (i < 128*640) {
    int n = i / 640, k = i - n*640;
    float v;
    if (k < 128) {
      v = Wu[(size_t)k*128 + n];
    } else {
      const int j = k - 128;
      v = 0.f;
      if (j < 256) {
        for (int m = 0; m < 256; ++m)
          v = fmaf(Wm2[(size_t)j*256 + m], Wu[(size_t)(128+m)*128 + n], v);
      } else {
        for (int m = 0; m < 256; ++m)
          v = fmaf(Wr2[(size_t)(j-256)*256 + m], Wu[(size_t)(128+m)*128 + n], v);
      }
    }
    WuT[i] = (_Float16)v;
  }
  if (i < 128) {
    float a1 = 0.f, a2 = 0.f;
    for (int m = 0; m < 256; ++m) {
      const float wu = Wu[(size_t)(128+m)*128 + i];
      a1 = fmaf(bm2[m], wu, a1);
      a2 = fmaf(br2[m], wu, a2);
    }
    c1[i] = a1; c2[i] = a2;
  }
}

// WceTh[16][512] = fp16((W2cat @ We1)^T) ; bce[16] = (bm2+br2)@We1 + be1
__global__ __launch_bounds__(256) void k_prep_wce(
    const float* __restrict__ Wm2, const float* __restrict__ Wr2,
    const float* __restrict__ We1, const float* __restrict__ bm2,
    const float* __restrict__ br2, const float* __restrict__ be1,
    _Float16* __restrict__ WceTh, float* __restrict__ bce)
{
  int i = blockIdx.x * 256 + threadIdx.x;
  if (i < 16*512) {
    int j = i >> 9, k = i & 511;
    float a = 0.f;
    for (int m = 0; m < 256; ++m) {
      const float w2 = (k < 256) ? Wm2[(size_t)k*256 + m] : Wr2[(size_t)(k-256)*256 + m];
      a = fmaf(w2, We1[(size_t)m*TD_ + j], a);
    }
    WceTh[(size_t)j*512 + k] = (_Float16)a;
  }
  if (i < 16) {
    float a = be1[i];
    for (int m = 0; m < 256; ++m) a = fmaf(bm2[m] + br2[m], We1[(size_t)m*TD_ + i], a);
    bce[i] = a;
  }
}

// ---------------- encoders ----------------
__global__ __launch_bounds__(128) void k_node_enc(
    const float* __restrict__ nf, const float* __restrict__ Wn,
    const float* __restrict__ bn, float* __restrict__ h, _Float16* __restrict__ hb)
{
  int n = blockIdx.x, j = threadIdx.x;
  __shared__ float xs[NF_];
  if (j < NF_) xs[j] = nf[(size_t)n*NF_ + j];
  __syncthreads();
  float a = bn[j];
  #pragma unroll
  for (int k = 0; k < NF_; ++k) a = fmaf(xs[k], Wn[(size_t)k*D_ + j], a);
  h[(size_t)n*D_ + j] = a;
  hb[(size_t)n*D_ + j] = (_Float16)a;
}

__global__ __launch_bounds__(128) void k_edge_enc(
    const float* __restrict__ ef, const float* __restrict__ We,
    const float* __restrict__ be, _Float16* __restrict__ eb)
{
  int i = blockIdx.x, j = threadIdx.x;
  __shared__ float xs[EF_];
  if (j < EF_) xs[j] = ef[(size_t)i*EF_ + j];
  __syncthreads();
  float a = be[j];
  #pragma unroll
  for (int k = 0; k < EF_; ++k) a = fmaf(xs[k], We[(size_t)k*D_ + j], a);
  eb[(size_t)i*D_ + j] = (_Float16)a;
}

// ---------------- GEMM: FT = hb @ W1Tn  (M=9216, N=1024, K=128) ----------------
__global__ __launch_bounds__(256) void k_gemm_FT(
    const _Float16* __restrict__ A, const _Float16* __restrict__ Bm,
    _Float16* __restrict__ FT)
{
  const int m0 = blockIdx.x * 128, n0 = blockIdx.y * 128;
  __shared__ _Float16 As[128*64], Bs[128*64];
  const int tid = threadIdx.x;
  const int srow = tid >> 3, slot = tid & 7;
  const int wave = tid >> 6, lane = tid & 63;
  const int wm = wave >> 1, wn = wave & 1;
  const int lr = lane & 15, lk = lane >> 4;
  f32x4 acc[4][4] = {};
  for (int kt = 0; kt < 2; ++kt) {
    __syncthreads();
    #pragma unroll
    for (int i = 0; i < 4; ++i) {
      const int r = srow + 32*i;
      const int ss = slot ^ (r & 7);
      gload16(A + (size_t)(m0 + r)*128 + kt*64 + ss*8, &As[r*64 + slot*8]);
      gload16(Bm + (size_t)(n0 + r)*128 + kt*64 + ss*8, &Bs[r*64 + slot*8]);
    }
    __syncthreads();
    #pragma unroll
    for (int ks = 0; ks < 2; ++ks) {
      f16x8 af[4], bfr[4];
      #pragma unroll
      for (int mf = 0; mf < 4; ++mf) {
        const int r = wm*64 + mf*16 + lr;
        const int ch = (ks*4 + lk) ^ (r & 7);
        af[mf] = *(const f16x8*)&As[r*64 + ch*8];
      }
      #pragma unroll
      for (int nf = 0; nf < 4; ++nf) {
        const int n = wn*64 + nf*16 + lr;
        const int ch = (ks*4 + lk) ^ (n & 7);
        bfr[nf] = *(const f16x8*)&Bs[n*64 + ch*8];
      }
      #pragma unroll
      for (int mf = 0; mf < 4; ++mf)
        #pragma unroll
        for (int nf = 0; nf < 4; ++nf)
          acc[mf][nf] = __builtin_amdgcn_mfma_f32_16x16x32_f16(af[mf], bfr[nf], acc[mf][nf], 0, 0, 0);
    }
  }
  #pragma unroll
  for (int nf = 0; nf < 4; ++nf) {
    const int c = n0 + wn*64 + nf*16 + lr;
    #pragma unroll
    for (int mf = 0; mf < 4; ++mf)
      #pragma unroll
      for (int v = 0; v < 4; ++v) {
        const int r = m0 + wm*64 + mf*16 + lk*4 + v;
        FT[(size_t)r*1024 + c] = (_Float16)acc[mf][nf][v];
      }
  }
}

// ---------------- GEMM: E = eb @ W1Te + bcat1  (M=51200, N=512, K=128) ----------------
__global__ __launch_bounds__(256) void k_gemm_E(
    const _Float16* __restrict__ A, const _Float16* __restrict__ Bm,
    const float* __restrict__ bcat1, _Float16* __restrict__ E)
{
  const int m0 = blockIdx.x * 128, n0 = blockIdx.y * 128;
  __shared__ _Float16 As[128*64], Bs[128*64];
  const int tid = threadIdx.x;
  const int srow = tid >> 3, slot = tid & 7;
  const int wave = tid >> 6, lane = tid & 63;
  const int wm = wave >> 1, wn = wave & 1;
  const int lr = lane & 15, lk = lane >> 4;
  f32x4 acc[4][4] = {};
  for (int kt = 0; kt < 2; ++kt) {
    __syncthreads();
    #pragma unroll
    for (int i = 0; i < 4; ++i) {
      const int r = srow + 32*i;
      const int ss = slot ^ (r & 7);
      gload16(A + (size_t)(m0 + r)*128 + kt*64 + ss*8, &As[r*64 + slot*8]);
      gload16(Bm + (size_t)(n0 + r)*128 + kt*64 + ss*8, &Bs[r*64 + slot*8]);
    }
    __syncthreads();
    #pragma unroll
    for (int ks = 0; ks < 2; ++ks) {
      f16x8 af[4], bfr[4];
      #pragma unroll
      for (int mf = 0; mf < 4; ++mf) {
        const int r = wm*64 + mf*16 + lr;
        const int ch = (ks*4 + lk) ^ (r & 7);
        af[mf] = *(const f16x8*)&As[r*64 + ch*8];
      }
      #pragma unroll
      for (int nf = 0; nf < 4; ++nf) {
        const int n = wn*64 + nf*16 + lr;
        const int ch = (ks*4 + lk) ^ (n & 7);
        bfr[nf] = *(const f16x8*)&Bs[n*64 + ch*8];
      }
      #pragma unroll
      for (int mf = 0; mf < 4; ++mf)
        #pragma unroll
        for (int nf = 0; nf < 4; ++nf)
          acc[mf][nf] = __builtin_amdgcn_mfma_f32_16x16x32_f16(af[mf], bfr[nf], acc[mf][nf], 0, 0, 0);
    }
  }
  #pragma unroll
  for (int nf = 0; nf < 4; ++nf) {
    const int c = n0 + wn*64 + nf*16 + lr;
    const float bias = bcat1[c];
    #pragma unroll
    for (int mf = 0; mf < 4; ++mf)
      #pragma unroll
      for (int v = 0; v < 4; ++v) {
        const int r = m0 + wm*64 + mf*16 + lk*4 + v;
        E[(size_t)r*512 + c] = (_Float16)(acc[mf][nf][v] + bias);
      }
  }
}

// ---------------- fused hidden + deterministic segment-sum (1 wave/node, f16x8) ----------------
__global__ __launch_bounds__(64) void k_agg_fused(
    const _Float16* __restrict__ FT, const _Float16* __restrict__ E,
    const int* __restrict__ from_idx, const int* __restrict__ to_idx,
    const int* __restrict__ in_cnt, const int* __restrict__ in_list,
    const int* __restrict__ out_cnt, const int* __restrict__ out_list,
    _Float16* __restrict__ Hsum)
{
  const int g = blockIdx.x;
  const int b = g / NPB_;
  const int lane = threadIdx.x;
  const int half = lane >> 5;          // 0 = in, 1 = out
  const int c8 = (lane & 31) * 8;      // element offset within 256
  const int ebase = b * EPB_;
  const size_t ftg = (size_t)g * 1024;

  const f16x8 base = (half == 0) ? *(const f16x8*)&FT[ftg + 512 + c8]    // T[n]
                                 : *(const f16x8*)&FT[ftg + 256 + c8];   // F[n] (r-part)
  const int cnt = (half == 0) ? in_cnt[g] : out_cnt[g];
  const int* lst = (half == 0) ? &in_list[(size_t)g*DEGCAP_] : &out_list[(size_t)g*DEGCAP_];
  const int eoff = half * 256;
  const int foff = (half == 0) ? 0 : 768;

  float acc[8] = {};
  for (int i = 0; i < cnt; ++i) {
    const int ge = ebase + lst[i];
    const int other = (half == 0) ? from_idx[ge] : to_idx[ge];
    const f16x8 fo = *(const f16x8*)&FT[(size_t)other*1024 + foff + c8];
    const f16x8 ev = *(const f16x8*)&E[(size_t)ge*512 + eoff + c8];
    #pragma unroll
    for (int k = 0; k < 8; ++k)
      acc[k] += fmaxf((float)base[k] + (float)fo[k] + (float)ev[k], 0.f);
  }
  f16x8 o;
  #pragma unroll
  for (int k = 0; k < 8; ++k) o[k] = (_Float16)acc[k];
  *(f16x8*)&Hsum[(size_t)g*512 + eoff + c8] = o;
}

// ---------------- fused GEMM: hn = [hb | Hsum] @ WuT + ic*c1 + oc*c2 + bu ----------------
// M=9216, N=128, K=640.  BM=64 -> 144 blocks for better CU coverage.
__global__ __launch_bounds__(256) void k_gemm_upd(
    const _Float16* __restrict__ hb, const _Float16* __restrict__ Hsum,
    const _Float16* __restrict__ WuT,
    const int* __restrict__ in_cnt, const int* __restrict__ out_cnt,
    const float* __restrict__ c1, const float* __restrict__ c2,
    const float* __restrict__ bu,
    float* __restrict__ hn, _Float16* __restrict__ hbn)
{
  const int m0 = blockIdx.x * 64;
  __shared__ _Float16 As[64*64];    // 8 KB
  __shared__ _Float16 Bs[128*64];   // 16 KB
  const int tid = threadIdx.x;
  const int wave = tid >> 6, lane = tid & 63;
  const int wm = wave >> 1, wn = wave & 1;   // wm: 32-row half, wn: 64-col half
  const int lr = lane & 15, lk = lane >> 4;
  f32x4 acc[2][4] = {};
  for (int kt = 0; kt < 10; ++kt) {
    __syncthreads();
    #pragma unroll
    for (int i = 0; i < 2; ++i) {          // A: 64 rows x 8 chunks = 512 slots
      const int sidx = tid + i*256;
      const int r = sidx >> 3, sl = sidx & 7;
      const int ss = sl ^ (r & 7);
      const _Float16* asrc = (kt < 2)
          ? hb   + (size_t)(m0 + r)*128 + kt*64 + ss*8
          : Hsum + (size_t)(m0 + r)*512 + (kt - 2)*64 + ss*8;
      gload16(asrc, &As[r*64 + sl*8]);
    }
    #pragma unroll
    for (int i = 0; i < 4; ++i) {          // B: 128 n x 8 chunks = 1024 slots
      const int sidx = tid + i*256;
      const int n = sidx >> 3, sl = sidx & 7;
      const int ss = sl ^ (n & 7);
      gload16(WuT + (size_t)n*640 + kt*64 + ss*8, &Bs[n*64 + sl*8]);
    }
    __syncthreads();
    #pragma unroll
    for (int ks = 0; ks < 2; ++ks) {
      f16x8 af[2], bfr[4];
      #pragma unroll
      for (int mf = 0; mf < 2; ++mf) {
        const int r = wm*32 + mf*16 + lr;
        const int ch = (ks*4 + lk) ^ (r & 7);
        af[mf] = *(const f16x8*)&As[r*64 + ch*8];
      }
      #pragma unroll
      for (int nf = 0; nf < 4; ++nf) {
        const int n = wn*64 + nf*16 + lr;
        const int ch = (ks*4 + lk) ^ (n & 7);
        bfr[nf] = *(const f16x8*)&Bs[n*64 + ch*8];
      }
      #pragma unroll
      for (int mf = 0; mf < 2; ++mf)
        #pragma unroll
        for (int nf = 0; nf < 4; ++nf)
          acc[mf][nf] = __builtin_amdgcn_mfma_f32_16x16x32_f16(af[mf], bfr[nf], acc[mf][nf], 0, 0, 0);
    }
  }
  #pragma unroll
  for (int nf = 0; nf < 4; ++nf) {
    const int c = wn*64 + nf*16 + lr;
    const float b1 = c1[c], b2 = c2[c], b0 = bu[c];
    #pragma unroll
    for (int mf = 0; mf < 2; ++mf)
      #pragma unroll
      for (int v = 0; v < 4; ++v) {
        const int r = m0 + wm*32 + mf*16 + lk*4 + v;
        const float o = acc[mf][nf][v] + in_cnt[r]*b1 + out_cnt[r]*b2 + b0;
        hn[(size_t)r*128 + c] = o;
        hbn[(size_t)r*128 + c] = (_Float16)o;
      }
  }
}

// ---------------- node target embeddings ----------------
__global__ __launch_bounds__(128) void k_node_emb(
    const float* __restrict__ h,
    const float* __restrict__ Wq1, const float* __restrict__ bq1,
    const float* __restrict__ Wq2, const float* __restrict__ bq2,
    float* __restrict__ tq_emb, float* __restrict__ tc_emb)
{
  const int bid = blockIdx.x;
  const int b = bid / (2*NMAX_), s = bid - b*(2*NMAX_);
  const bool isQ = s < NMAX_;
  const int r = isQ ? s : s - NMAX_;
  float* outp = (isQ ? tq_emb : tc_emb) + ((size_t)b*NMAX_ + r)*TD_;
  const int tid = threadIdx.x;
  if (isQ && r >= NQ_) {
    if (tid < TD_) outp[tid] = 0.f;
    return;
  }
  const int node = b*NPB_ + (isQ ? r : NQ_ + r);
  __shared__ float xs[D_];
  __shared__ float l1[TD_];
  xs[tid] = h[(size_t)node*D_ + tid];
  __syncthreads();
  if (tid < TD_) {
    float a = bq1[tid];
    for (int k = 0; k < D_; ++k) a = fmaf(xs[k], Wq1[(size_t)k*TD_ + tid], a);
    l1[tid] = fmaxf(a, 0.f);
  }
  __syncthreads();
  if (tid < TD_) {
    float a = bq2[tid];
    #pragma unroll
    for (int k = 0; k < TD_; ++k) a = fmaf(l1[k], Wq2[(size_t)k*TD_ + tid], a);
    outp[tid] = a;
  }
}

// ---------------- sinkhorn over 40x40 node plans ----------------
__global__ __launch_bounds__(256) void k_sinkhorn_n(
    const float* __restrict__ tq_emb, const float* __restrict__ tc_emb,
    float* __restrict__ plan_n)
{
  const int b = blockIdx.x, tid = threadIdx.x;
  __shared__ float la[NMAX_][NMAX_];
  __shared__ float qe[NMAX_][TD_], ce[NMAX_][TD_];
  for (int idx = tid; idx < NMAX_*TD_; idx += 256) {
    qe[idx / TD_][idx % TD_] = tq_emb[(size_t)b*NMAX_*TD_ + idx];
    ce[idx / TD_][idx % TD_] = tc_emb[(size_t)b*NMAX_*TD_ + idx];
  }
  __syncthreads();
  for (int idx = tid; idx < NMAX_*NMAX_; idx += 256) {
    int q = idx / NMAX_, c = idx - q*NMAX_;
    float a = 0.f;
    #pragma unroll
    for (int d = 0; d < TD_; ++d) a = fmaf(qe[q][d], ce[c][d], a);
    la[q][c] = a * L2E10_;
  }
  __syncthreads();
  for (int it = 0; it < ITERS_; ++it) {
    if (tid < NMAX_) {
      float m = -INFINITY;
      for (int c = 0; c < NMAX_; ++c) m = fmaxf(m, la[tid][c]);
      float s = 0.f;
      for (int c = 0; c < NMAX_; ++c) s += ex2(la[tid][c] - m);
      const float lse = m + lg2(s);
      for (int c = 0; c < NMAX_; ++c) la[tid][c] -= lse;
    }
    __syncthreads();
    if (tid < NMAX_) {
      float m = -INFINITY;
      for (int q = 0; q < NMAX_; ++q) m = fmaxf(m, la[q][tid]);
      float s = 0.f;
      for (int q = 0; q < NMAX_; ++q) s += ex2(la[q][tid] - m);
      const float lse = m + lg2(s);
      for (int q = 0; q < NMAX_; ++q) la[q][tid] -= lse;
    }
    __syncthreads();
  }
  for (int idx = tid; idx < NMAX_*NMAX_; idx += 256)
    plan_n[(size_t)b*NMAX_*NMAX_ + idx] = ex2(la[idx / NMAX_][idx % NMAX_]);
}

// ---------------- final edge embed via MFMA ----------------
__global__ __launch_bounds__(256) void k_edge_emb_f(
    const _Float16* __restrict__ FT, const _Float16* __restrict__ E,
    const int* __restrict__ from_idx, const int* __restrict__ to_idx,
    const _Float16* __restrict__ WceTh, const float* __restrict__ bce,
    const float* __restrict__ We2, const float* __restrict__ be2,
    float* __restrict__ teq, float* __restrict__ tec)
{
  __shared__ _Float16 smem[64 * 512];   // 64 KB; wave w owns smem + w*8192
  const int tid = threadIdx.x;
  const int w = tid >> 6, lane = tid & 63;
  const int lr = lane & 15, lk = lane >> 4;
  _Float16* esw = smem + w * 8192;      // 16 rows x 512 (64 chunks x 8)
  const int e0 = blockIdx.x * 64 + w * 16;

  f16x8 bfrag[16];
  #pragma unroll
  for (int ks = 0; ks < 16; ++ks)
    bfrag[ks] = *(const f16x8*)&WceTh[(size_t)lr*512 + (size_t)(ks*4 + lk)*8];

  for (int i = 0; i < 16; ++i) {
    const int ge = e0 + i;
    const int sf = from_idx[ge], st = to_idx[ge];
    const int c8 = lane * 8;
    const f16x8 fa = *(const f16x8*)&FT[(size_t)sf*1024 + c8];
    const f16x8 fb = *(const f16x8*)&FT[(size_t)st*1024 + 512 + c8];
    const f16x8 ev = *(const f16x8*)&E[(size_t)ge*512 + c8];
    f16x8 o;
    #pragma unroll
    for (int k = 0; k < 8; ++k)
      o[k] = (_Float16)fmaxf((float)fa[k] + (float)fb[k] + (float)ev[k], 0.f);
    *(f16x8*)&esw[i*512 + ((lane ^ (i & 7)) * 8)] = o;
  }
  __syncthreads();

  f32x4 acc = {};
  #pragma unroll
  for (int ks = 0; ks < 16; ++ks) {
    const int ch = (ks*4 + lk) ^ (lr & 7);
    const f16x8 af = *(const f16x8*)&esw[lr*512 + ch*8];
    acc = __builtin_amdgcn_mfma_f32_16x16x32_f16(af, bfrag[ks], acc, 0, 0, 0);
  }
  __syncthreads();

  float* l1f = (float*)esw;
  const float bc = bce[lr];
  #pragma unroll
  for (int v = 0; v < 4; ++v)
    l1f[(lk*4 + v)*16 + lr] = fmaxf(acc[v] + bc, 0.f);
  __syncthreads();

  const float b2 = be2[lr];
  #pragma unroll
  for (int v = 0; v < 4; ++v) {
    const int e = lk*4 + v;
    float a = b2;
    #pragma unroll
    for (int k = 0; k < TD_; ++k) a = fmaf(l1f[e*16 + k], We2[(size_t)k*TD_ + lr], a);
    const int ei = e0 + e;
    const int bb = ei / EPB_, jl = ei - bb*EPB_;
    if (jl < EQ_) teq[((size_t)bb*EMAX_ + jl)*TD_ + lr] = a;
    else          tec[((size_t)bb*EMAX_ + (jl - EQ_))*TD_ + lr] = a;
  }
}

// ---------------- fused: escore + sinkhorn_e (registers) + final score ----------------
// Col sums reuse row-softmax p[]/s (no col ex2); row/col lse subtraction fused.
__global__ __launch_bounds__(1024) void k_plan_score(
    const float* __restrict__ teq, const float* __restrict__ tec,
    const float* __restrict__ plan_n,
    const float* __restrict__ tq_emb, const float* __restrict__ tc_emb,
    const int* __restrict__ fq, const int* __restrict__ tq,
    const int* __restrict__ fc, const int* __restrict__ tc,
    const float* __restrict__ Wa, const float* __restrict__ ba,
    float* __restrict__ out)
{
  const int b = blockIdx.x, t = threadIdx.x;
  const int tr = t >> 4, tcg = t & 15, lane = t & 63, w = t >> 6;

  __shared__ float shm[8704];    // overlay: {sq,sc} | wovs | epilogue tables
  __shared__ float bcast[256];

  {
    float* sq = shm;             // 256*17
    float* sc = shm + 4352;      // 256*17
    for (int idx = t; idx < 4096; idx += 1024) {
      const int r = idx >> 4, k = idx & 15;
      sq[r*17 + k] = teq[(size_t)b*4096 + idx];
      sc[r*17 + k] = tec[(size_t)b*4096 + idx];
    }
  }
  __syncthreads();

  float la[4][16];
  {
    const float* sq = shm;
    const float* sc = shm + 4352;
    #pragma unroll
    for (int i = 0; i < 4; ++i)
      #pragma unroll
      for (int j = 0; j < 16; ++j) la[i][j] = 0.f;
    for (int k = 0; k < 16; ++k) {
      float qk[4];
      #pragma unroll
      for (int i = 0; i < 4; ++i) qk[i] = sq[(tr*4 + i)*17 + k];
      #pragma unroll
      for (int j = 0; j < 16; ++j) {
        const float sck = sc[(j*16 + tcg)*17 + k];
        #pragma unroll
        for (int i = 0; i < 4; ++i) la[i][j] = fmaf(qk[i], sck, la[i][j]);
      }
    }
    #pragma unroll
    for (int i = 0; i < 4; ++i)
      #pragma unroll
      for (int j = 0; j < 16; ++j) la[i][j] *= L2E10_;
  }
  __syncthreads();   // sq/sc dead; shm reused as wovs

  float* wovs = shm;           // 4096

  for (int it = 0; it < ITERS_; ++it) {
    float lsei[4];
    float colacc[16];
    #pragma unroll
    for (int j = 0; j < 16; ++j) colacc[j] = 0.f;
    // ---- row pass: compute row lse; accumulate col partials from p/s ----
    #pragma unroll
    for (int i = 0; i < 4; ++i) {
      float m = fmaxf(
        fmaxf(fmaxf(fmaxf(la[i][0],la[i][1]), fmaxf(la[i][2],la[i][3])),
              fmaxf(fmaxf(la[i][4],la[i][5]), fmaxf(la[i][6],la[i][7]))),
        fmaxf(fmaxf(fmaxf(la[i][8],la[i][9]), fmaxf(la[i][10],la[i][11])),
              fmaxf(fmaxf(la[i][12],la[i][13]), fmaxf(la[i][14],la[i][15]))));
      m = fmaxf(m, __shfl_xor(m, 1)); m = fmaxf(m, __shfl_xor(m, 2));
      m = fmaxf(m, __shfl_xor(m, 4)); m = fmaxf(m, __shfl_xor(m, 8));
      float p[16];
      #pragma unroll
      for (int j = 0; j < 16; ++j) p[j] = ex2(la[i][j] - m);
      float s = (((p[0]+p[1]) + (p[2]+p[3])) + ((p[4]+p[5]) + (p[6]+p[7])))
              + (((p[8]+p[9]) + (p[10]+p[11])) + ((p[12]+p[13]) + (p[14]+p[15])));
      s += __shfl_xor(s, 1); s += __shfl_xor(s, 2);
      s += __shfl_xor(s, 4); s += __shfl_xor(s, 8);
      const float sl2 = lg2(s);
      lsei[i] = m + sl2;
      const float rinv = ex2(-sl2);     // 1/s
      #pragma unroll
      for (int j = 0; j < 16; ++j) colacc[j] = fmaf(p[j], rinv, colacc[j]);
    }
    // ---- col partials across wave ----
    #pragma unroll
    for (int j = 0; j < 16; ++j) {
      float s = colacc[j];
      s += __shfl_xor(s, 16);
      s += __shfl_xor(s, 32);
      if (lane < 16) wovs[w*256 + j*16 + lane] = s;
    }
    __syncthreads();
    if (t < 256) {
      float s0 = 0.f, s1 = 0.f, s2 = 0.f, s3 = 0.f;
      #pragma unroll
      for (int ww = 0; ww < 16; ww += 4) {
        s0 += wovs[(ww+0)*256 + t];
        s1 += wovs[(ww+1)*256 + t];
        s2 += wovs[(ww+2)*256 + t];
        s3 += wovs[(ww+3)*256 + t];
      }
      bcast[t] = lg2(fmaxf((s0 + s1) + (s2 + s3), 1e-30f));
    }
    __syncthreads();
    // ---- fused subtraction of row lse + col lse ----
    #pragma unroll
    for (int j = 0; j < 16; ++j) {
      const float cj = bcast[j*16 + tcg];
      #pragma unroll
      for (int i = 0; i < 4; ++i) la[i][j] -= (lsei[i] + cj);
    }
  }
  __syncthreads();

  // ---- epilogue: overlay pn/qe/ce/indices into shm ----
  float* pn = shm;                 // 1600
  float* qe = shm + 1600;          // 640
  float* ce = shm + 2240;          // 640
  int*   ib = (int*)(shm + 2880);  // 800 ints
  int* sfq = ib, *stq = ib + 160, *sfc = ib + 320, *stc = ib + 560;
  for (int i = t; i < 1600; i += 1024) pn[i] = plan_n[(size_t)b*1600 + i];
  if (t < 640) { qe[t] = tq_emb[(size_t)b*640 + t]; ce[t] = tc_emb[(size_t)b*640 + t]; }
  if (t < 160) { sfq[t] = fq[b*160 + t]; stq[t] = tq[b*160 + t]; }
  if (t >= 512 && t < 752) { sfc[t-512] = fc[b*240 + (t-512)]; stc[t-512] = tc[b*240 + (t-512)]; }
  __syncthreads();

  float csum = 0.f;
  if (tr < 40) {
    #pragma unroll
    for (int i = 0; i < 4; ++i) {
      const int q = tr*4 + i;
      const int g0 = sfq[q]*NMAX_, g1 = stq[q]*NMAX_;
      #pragma unroll
      for (int j = 0; j < 15; ++j) {
        const int c = j*16 + tcg;
        const float pe = ex2(la[i][j]);
        const float a0 = pn[g0 + sfc[c]] * pn[g1 + stc[c]];
        const float a1 = pn[g0 + stc[c]] * pn[g1 + sfc[c]];
        csum += pe * fmaxf(a0, a1);
      }
    }
  }
  float hsum = 0.f;
  if (t < NMAX_*TD_) {
    const int q = t >> 4, d2 = t & 15;
    float a = 0.f;
    for (int c = 0; c < NMAX_; ++c) a = fmaf(pn[q*NMAX_ + c], ce[c*TD_ + d2], a);
    hsum = fmaxf(qe[t] - a, 0.f);
  }
  #pragma unroll
  for (int off = 32; off; off >>= 1) {
    csum += __shfl_xor(csum, off);
    hsum += __shfl_xor(hsum, off);
  }
  if (lane == 0) { bcast[w] = csum; bcast[32 + w] = hsum; }
  __syncthreads();
  if (t == 0) {
    float C = 0.f, H = 0.f;
    #pragma unroll
    for (int ww = 0; ww < 16; ++ww) { C += bcast[ww]; H += bcast[32 + ww]; }
    out[b] = (-H) * Wa[0] + C * Wa[1] + ba[0];
  }
}

// ---------------- host launcher ----------------
extern "C" void kernel_launch(void* const* d_in, const int* in_sizes, int n_in,
                              void* d_out, int out_size, void* d_ws, size_t ws_size,
                              hipStream_t stream) {
  const float* node_features = (const float*)d_in[0];
  const float* edge_features = (const float*)d_in[1];
  const float* Wn  = (const float*)d_in[2];
  const float* bn  = (const float*)d_in[3];
  const float* We  = (const float*)d_in[4];
  const float* be  = (const float*)d_in[5];
  const float* Wm1 = (const float*)d_in[6];
  const float* bm1 = (const float*)d_in[7];
  const float* Wm2 = (const float*)d_in[8];
  const float* bm2 = (const float*)d_in[9];
  const float* Wr1 = (const float*)d_in[10];
  const float* br1 = (const float*)d_in[11];
  const float* Wr2 = (const float*)d_in[12];
  const float* br2 = (const float*)d_in[13];
  const float* Wu  = (const float*)d_in[14];
  const float* bu  = (const float*)d_in[15];
  const float* Wq1 = (const float*)d_in[16];
  const float* bq1 = (const float*)d_in[17];
  const float* Wq2 = (const float*)d_in[18];
  const float* bq2 = (const float*)d_in[19];
  const float* We1 = (const float*)d_in[20];
  const float* be1 = (const float*)d_in[21];
  const float* We2 = (const float*)d_in[22];
  const float* be2 = (const float*)d_in[23];
  const float* Wa  = (const float*)d_in[24];
  const float* ba  = (const float*)d_in[25];
  const int* fq = (const int*)d_in[26];
  const int* tq = (const int*)d_in[27];
  const int* fc = (const int*)d_in[28];
  const int* tc = (const int*)d_in[29];
  (void)in_sizes; (void)n_in; (void)out_size; (void)ws_size;

  char* ws = (char*)d_ws;
  size_t off = 0;
  auto take = [&](size_t bytes) -> void* {
    void* p = ws + off;
    off = (off + bytes + 255) & ~(size_t)255;
    return p;
  };
  int*   from_idx = (int*)  take((size_t)ETOT_*4);
  int*   to_idx   = (int*)  take((size_t)ETOT_*4);
  int*   in_cnt   = (int*)  take((size_t)NTOT_*4);
  int*   out_cnt  = (int*)  take((size_t)NTOT_*4);
  int*   in_list  = (int*)  take((size_t)NTOT_*DEGCAP_*4);
  int*   out_list = (int*)  take((size_t)NTOT_*DEGCAP_*4);
  float* h0       = (float*)take((size_t)NTOT_*D_*4);
  float* h1       = (float*)take((size_t)NTOT_*D_*4);
  _Float16* hbA   = (_Float16*)take((size_t)NTOT_*D_*2);
  _Float16* hbB   = (_Float16*)take((size_t)NTOT_*D_*2);
  _Float16* eb    = (_Float16*)take((size_t)ETOT_*D_*2);
  _Float16* FT    = (_Float16*)take((size_t)NTOT_*1024*2);
  _Float16* Ebuf  = (_Float16*)take((size_t)ETOT_*512*2);
  _Float16* Hsum  = (_Float16*)take((size_t)NTOT_*512*2);
  float* tq_emb   = (float*)take((size_t)B_*NMAX_*TD_*4);
  float* tc_emb   = (float*)take((size_t)B_*NMAX_*TD_*4);
  float* plan_n   = (float*)take((size_t)B_*NMAX_*NMAX_*4);
  float* teq      = (float*)take((size_t)B_*EMAX_*TD_*4);
  float* tec      = (float*)take((size_t)B_*EMAX_*TD_*4);
  _Float16* W1Tn  = (_Float16*)take((size_t)1024*128*2);
  _Float16* W1Te  = (_Float16*)take((size_t)512*128*2);
  _Float16* WuT   = (_Float16*)take((size_t)128*640*2);
  float* bcat1    = (float*)take(512*4);
  float* c1       = (float*)take(128*4);
  float* c2       = (float*)take(128*4);
  _Float16* WceTh = (_Float16*)take((size_t)16*512*2);
  float* bce      = (float*)take(16*4);

  k_build_idx<<<(ETOT_ + 255)/256, 256, 0, stream>>>(fq, tq, fc, tc, from_idx, to_idx);
  k_build_lists<<<B_, 256, 0, stream>>>(fq, tq, fc, tc, in_cnt, in_list, out_cnt, out_list);
  k_prep_w<<<(1024*128 + 512*128)/256, 256, 0, stream>>>(
      Wm1, Wr1, bm1, br1, W1Tn, W1Te, bcat1);
  k_prep_wu<<<(128*640 + 255)/256, 256, 0, stream>>>(Wm2, Wr2, Wu, bm2, br2, WuT, c1, c2);
  k_prep_wce<<<32, 256, 0, stream>>>(Wm2, Wr2, We1, bm2, br2, be1, WceTh, bce);
  k_node_enc<<<NTOT_, D_, 0, stream>>>(node_features, Wn, bn, h0, hbA);
  k_edge_enc<<<ETOT_, D_, 0, stream>>>(edge_features, We, be, eb);

  dim3 gE(ETOT_/128, 4);
  k_gemm_E<<<gE, 256, 0, stream>>>(eb, W1Te, bcat1, Ebuf);

  dim3 gFT(NTOT_/128, 8);
  float* hc = h0;  float* hn = h1;
  _Float16* hbc = hbA;  _Float16* hbn = hbB;
  for (int p = 0; p < NPROP_; ++p) {
    k_gemm_FT<<<gFT, 256, 0, stream>>>(hbc, W1Tn, FT);
    k_agg_fused<<<NTOT_, 64, 0, stream>>>(FT, Ebuf, from_idx, to_idx,
                                          in_cnt, in_list, out_cnt, out_list, Hsum);
    k_gemm_upd<<<NTOT_/64, 256, 0, stream>>>(hbc, Hsum, WuT, in_cnt, out_cnt,
                                             c1, c2, bu, hn, hbn);
    float* tf = hc; hc = hn; hn = tf;
    _Float16* th = hbc; hbc = hbn; hbn = th;
  }

  k_node_emb<<<B_*2*NMAX_, D_, 0, stream>>>(hc, Wq1, bq1, Wq2, bq2, tq_emb, tc_emb);
  k_sinkhorn_n<<<B_, 256, 0, stream>>>(tq_emb, tc_emb, plan_n);

  k_gemm_FT<<<gFT, 256, 0, stream>>>(hbc, W1Tn, FT);
  hipMemsetAsync(teq, 0, (size_t)B_*EMAX_*TD_*4, stream);
  hipMemsetAsync(tec, 0, (size_t)B_*EMAX_*TD_*4, stream);
  k_edge_emb_f<<<ETOT_/64, 256, 0, stream>>>(FT, Ebuf, from_idx, to_idx,
                                             WceTh, bce, We2, be2, teq, tec);

  k_plan_score<<<B_, 1024, 0, stream>>>(teq, tec, plan_n, tq_emb, tc_emb,
                                        fq, tq, fc, tc, Wa, ba, (float*)d_out);
}

// Round 12
// 623.597 us; speedup vs baseline: 1.1230x; 1.1230x over previous
//
#include <hip/hip_runtime.h>
#include <cstddef>
#include <cstdint>

// ---------------- problem constants ----------------
constexpr int B_    = 128;
constexpr int NQ_   = 32;
constexpr int NC_   = 40;
constexpr int NMAX_ = 40;
constexpr int EQ_   = 160;
constexpr int EC_   = 240;
constexpr int EMAX_ = 256;
constexpr int D_    = 128;
constexpr int TD_   = 16;
constexpr int NPROP_ = 5;
constexpr int ITERS_ = 20;
constexpr float TEMP_ = 0.1f;
constexpr int NF_   = 32;
constexpr int EF_   = 16;
constexpr int NPB_  = NQ_ + NC_;   // 72 nodes / batch
constexpr int EPB_  = EQ_ + EC_;   // 400 edges / batch
constexpr int NTOT_ = B_ * NPB_;   // 9216
constexpr int ETOT_ = B_ * EPB_;   // 51200
constexpr int DEGCAP_ = 64;
constexpr float L2E10_ = 14.4269504088896f;  // 10 * log2(e)

typedef _Float16 f16x8 __attribute__((ext_vector_type(8)));
typedef _Float16 f16x4 __attribute__((ext_vector_type(4)));
typedef float f32x4 __attribute__((ext_vector_type(4)));

__device__ __forceinline__ void gload16(const void* g, void* l) {
  __builtin_amdgcn_global_load_lds(
      (const __attribute__((address_space(1))) unsigned int*)g,
      (__attribute__((address_space(3))) unsigned int*)l, 16, 0, 0);
}
__device__ __forceinline__ float ex2(float x) { return __builtin_amdgcn_exp2f(x); }
__device__ __forceinline__ float lg2(float x) { return __builtin_amdgcn_logf(x); }

// ---------------- index building ----------------
__global__ __launch_bounds__(256) void k_build_idx(
    const int* __restrict__ fq, const int* __restrict__ tq,
    const int* __restrict__ fc, const int* __restrict__ tc,
    int* __restrict__ from_idx, int* __restrict__ to_idx)
{
  int i = blockIdx.x * blockDim.x + threadIdx.x;
  if (i >= ETOT_) return;
  int b = i / EPB_, j = i - b * EPB_;
  int f, t;
  if (j < EQ_) {
    f = fq[b*EQ_ + j] + b*NPB_;
    t = tq[b*EQ_ + j] + b*NPB_;
  } else {
    int jj = j - EQ_;
    f = fc[b*EC_ + jj] + b*NPB_ + NQ_;
    t = tc[b*EC_ + jj] + b*NPB_ + NQ_;
  }
  from_idx[i] = f;
  to_idx[i]   = t;
}

// ---------------- per-node edge lists (deterministic ascending order) ----------------
__global__ __launch_bounds__(256) void k_build_lists(
    const int* __restrict__ fq, const int* __restrict__ tq,
    const int* __restrict__ fc, const int* __restrict__ tc,
    int* __restrict__ in_cnt, int* __restrict__ in_list,
    int* __restrict__ out_cnt, int* __restrict__ out_list)
{
  const int b = blockIdx.x, tid = threadIdx.x;
  __shared__ short sf[EPB_], st[EPB_];
  for (int j = tid; j < EPB_; j += 256) {
    int f, t;
    if (j < EQ_) { f = fq[b*EQ_ + j];              t = tq[b*EQ_ + j]; }
    else         { f = fc[b*EC_ + (j-EQ_)] + NQ_;  t = tc[b*EC_ + (j-EQ_)] + NQ_; }
    sf[j] = (short)f; st[j] = (short)t;
  }
  __syncthreads();
  if (tid < NPB_) {
    const int g = b*NPB_ + tid;
    int ic = 0, oc = 0;
    for (int j = 0; j < EPB_; ++j) {
      if ((int)st[j] == tid && ic < DEGCAP_) in_list[g*DEGCAP_ + (ic++)] = j;
      if ((int)sf[j] == tid && oc < DEGCAP_) out_list[g*DEGCAP_ + (oc++)] = j;
    }
    in_cnt[g] = ic; out_cnt[g] = oc;
  }
}

// ---------------- weight prep: W1Tn, W1Te, bcat1 ----------------
__global__ __launch_bounds__(256) void k_prep_w(
    const float* __restrict__ Wm1, const float* __restrict__ Wr1,
    const float* __restrict__ bm1, const float* __restrict__ br1,
    _Float16* __restrict__ W1Tn, _Float16* __restrict__ W1Te,
    float* __restrict__ bcat1)
{
  int i = blockIdx.x * 256 + threadIdx.x;
  if (i < 1024*128) {
    int n = i >> 7, k = i & 127;
    float v;
    if (n < 512) {            // F-part: W1 row k
      v = (n < 256) ? Wm1[(size_t)k*256 + n]
                    : Wr1[(size_t)(k + 128)*256 + (n - 256)];
    } else {                  // T-part: W1 row 128+k
      int n2 = n - 512;
      v = (n2 < 256) ? Wm1[(size_t)(128 + k)*256 + n2]
                     : Wr1[(size_t)k*256 + (n2 - 256)];
    }
    W1Tn[i] = (_Float16)v;
  }
  int j = i - 1024*128;
  if (j >= 0 && j < 512*128) {
    int n = j >> 7, k = j & 127;   // W1 row 256+k
    float v = (n < 256) ? Wm1[(size_t)(256 + k)*256 + n]
                        : Wr1[(size_t)(256 + k)*256 + (n - 256)];
    W1Te[j] = (_Float16)v;
  }
  if (i < 512) bcat1[i] = (i < 256) ? bm1[i] : br1[i - 256];
}

// ---------------- fused update-weight prep ----------------
__global__ __launch_bounds__(256) void k_prep_wu(
    const float* __restrict__ Wm2, const float* __restrict__ Wr2,
    const float* __restrict__ Wu,
    const float* __restrict__ bm2, const float* __restrict__ br2,
    _Float16* __restrict__ WuT, float* __restrict__ c1, float* __restrict__ c2)
{
  int i = blockIdx.x * 256 + threadIdx.x;
  if (i < 128*640) {
    int n = i / 640, k = i - n*640;
    float v;
    if (k < 128) {
      v = Wu[(size_t)k*128 + n];
    } else {
      const int j = k - 128;
      v = 0.f;
      if (j < 256) {
        for (int m = 0; m < 256; ++m)
          v = fmaf(Wm2[(size_t)j*256 + m], Wu[(size_t)(128+m)*128 + n], v);
      } else {
        for (int m = 0; m < 256; ++m)
          v = fmaf(Wr2[(size_t)(j-256)*256 + m], Wu[(size_t)(128+m)*128 + n], v);
      }
    }
    WuT[i] = (_Float16)v;
  }
  if (i < 128) {
    float a1 = 0.f, a2 = 0.f;
    for (int m = 0; m < 256; ++m) {
      const float wu = Wu[(size_t)(128+m)*128 + i];
      a1 = fmaf(bm2[m], wu, a1);
      a2 = fmaf(br2[m], wu, a2);
    }
    c1[i] = a1; c2[i] = a2;
  }
}

// WceTh[16][512] = fp16((W2cat @ We1)^T) ; bce[16] = (bm2+br2)@We1 + be1
__global__ __launch_bounds__(256) void k_prep_wce(
    const float* __restrict__ Wm2, const float* __restrict__ Wr2,
    const float* __restrict__ We1, const float* __restrict__ bm2,
    const float* __restrict__ br2, const float* __restrict__ be1,
    _Float16* __restrict__ WceTh, float* __restrict__ bce)
{
  int i = blockIdx.x * 256 + threadIdx.x;
  if (i < 16*512) {
    int j = i >> 9, k = i & 511;
    float a = 0.f;
    for (int m = 0; m < 256; ++m) {
      const float w2 = (k < 256) ? Wm2[(size_t)k*256 + m] : Wr2[(size_t)(k-256)*256 + m];
      a = fmaf(w2, We1[(size_t)m*TD_ + j], a);
    }
    WceTh[(size_t)j*512 + k] = (_Float16)a;
  }
  if (i < 16) {
    float a = be1[i];
    for (int m = 0; m < 256; ++m) a = fmaf(bm2[m] + br2[m], We1[(size_t)m*TD_ + i], a);
    bce[i] = a;
  }
}

// ---------------- encoders ----------------
__global__ __launch_bounds__(128) void k_node_enc(
    const float* __restrict__ nf, const float* __restrict__ Wn,
    const float* __restrict__ bn, float* __restrict__ h, _Float16* __restrict__ hb)
{
  int n = blockIdx.x, j = threadIdx.x;
  __shared__ float xs[NF_];
  if (j < NF_) xs[j] = nf[(size_t)n*NF_ + j];
  __syncthreads();
  float a = bn[j];
  #pragma unroll
  for (int k = 0; k < NF_; ++k) a = fmaf(xs[k], Wn[(size_t)k*D_ + j], a);
  h[(size_t)n*D_ + j] = a;
  hb[(size_t)n*D_ + j] = (_Float16)a;
}

__global__ __launch_bounds__(128) void k_edge_enc(
    const float* __restrict__ ef, const float* __restrict__ We,
    const float* __restrict__ be, _Float16* __restrict__ eb)
{
  int i = blockIdx.x, j = threadIdx.x;
  __shared__ float xs[EF_];
  if (j < EF_) xs[j] = ef[(size_t)i*EF_ + j];
  __syncthreads();
  float a = be[j];
  #pragma unroll
  for (int k = 0; k < EF_; ++k) a = fmaf(xs[k], We[(size_t)k*D_ + j], a);
  eb[(size_t)i*D_ + j] = (_Float16)a;
}

// ---------------- GEMM: FT = hb @ W1Tn  (M=9216, N=1024, K=128) ----------------
__global__ __launch_bounds__(256) void k_gemm_FT(
    const _Float16* __restrict__ A, const _Float16* __restrict__ Bm,
    _Float16* __restrict__ FT)
{
  const int m0 = blockIdx.x * 128, n0 = blockIdx.y * 128;
  __shared__ _Float16 As[128*64], Bs[128*64];
  const int tid = threadIdx.x;
  const int srow = tid >> 3, slot = tid & 7;
  const int wave = tid >> 6, lane = tid & 63;
  const int wm = wave >> 1, wn = wave & 1;
  const int lr = lane & 15, lk = lane >> 4;
  f32x4 acc[4][4] = {};
  for (int kt = 0; kt < 2; ++kt) {
    __syncthreads();
    #pragma unroll
    for (int i = 0; i < 4; ++i) {
      const int r = srow + 32*i;
      const int ss = slot ^ (r & 7);
      gload16(A + (size_t)(m0 + r)*128 + kt*64 + ss*8, &As[r*64 + slot*8]);
      gload16(Bm + (size_t)(n0 + r)*128 + kt*64 + ss*8, &Bs[r*64 + slot*8]);
    }
    __syncthreads();
    #pragma unroll
    for (int ks = 0; ks < 2; ++ks) {
      f16x8 af[4], bfr[4];
      #pragma unroll
      for (int mf = 0; mf < 4; ++mf) {
        const int r = wm*64 + mf*16 + lr;
        const int ch = (ks*4 + lk) ^ (r & 7);
        af[mf] = *(const f16x8*)&As[r*64 + ch*8];
      }
      #pragma unroll
      for (int nf = 0; nf < 4; ++nf) {
        const int n = wn*64 + nf*16 + lr;
        const int ch = (ks*4 + lk) ^ (n & 7);
        bfr[nf] = *(const f16x8*)&Bs[n*64 + ch*8];
      }
      #pragma unroll
      for (int mf = 0; mf < 4; ++mf)
        #pragma unroll
        for (int nf = 0; nf < 4; ++nf)
          acc[mf][nf] = __builtin_amdgcn_mfma_f32_16x16x32_f16(af[mf], bfr[nf], acc[mf][nf], 0, 0, 0);
    }
  }
  #pragma unroll
  for (int nf = 0; nf < 4; ++nf) {
    const int c = n0 + wn*64 + nf*16 + lr;
    #pragma unroll
    for (int mf = 0; mf < 4; ++mf)
      #pragma unroll
      for (int v = 0; v < 4; ++v) {
        const int r = m0 + wm*64 + mf*16 + lk*4 + v;
        FT[(size_t)r*1024 + c] = (_Float16)acc[mf][nf][v];
      }
  }
}

// ---------------- GEMM: E = eb @ W1Te + bcat1  (M=51200, N=512, K=128) ----------------
__global__ __launch_bounds__(256) void k_gemm_E(
    const _Float16* __restrict__ A, const _Float16* __restrict__ Bm,
    const float* __restrict__ bcat1, _Float16* __restrict__ E)
{
  const int m0 = blockIdx.x * 128, n0 = blockIdx.y * 128;
  __shared__ _Float16 As[128*64], Bs[128*64];
  const int tid = threadIdx.x;
  const int srow = tid >> 3, slot = tid & 7;
  const int wave = tid >> 6, lane = tid & 63;
  const int wm = wave >> 1, wn = wave & 1;
  const int lr = lane & 15, lk = lane >> 4;
  f32x4 acc[4][4] = {};
  for (int kt = 0; kt < 2; ++kt) {
    __syncthreads();
    #pragma unroll
    for (int i = 0; i < 4; ++i) {
      const int r = srow + 32*i;
      const int ss = slot ^ (r & 7);
      gload16(A + (size_t)(m0 + r)*128 + kt*64 + ss*8, &As[r*64 + slot*8]);
      gload16(Bm + (size_t)(n0 + r)*128 + kt*64 + ss*8, &Bs[r*64 + slot*8]);
    }
    __syncthreads();
    #pragma unroll
    for (int ks = 0; ks < 2; ++ks) {
      f16x8 af[4], bfr[4];
      #pragma unroll
      for (int mf = 0; mf < 4; ++mf) {
        const int r = wm*64 + mf*16 + lr;
        const int ch = (ks*4 + lk) ^ (r & 7);
        af[mf] = *(const f16x8*)&As[r*64 + ch*8];
      }
      #pragma unroll
      for (int nf = 0; nf < 4; ++nf) {
        const int n = wn*64 + nf*16 + lr;
        const int ch = (ks*4 + lk) ^ (n & 7);
        bfr[nf] = *(const f16x8*)&Bs[n*64 + ch*8];
      }
      #pragma unroll
      for (int mf = 0; mf < 4; ++mf)
        #pragma unroll
        for (int nf = 0; nf < 4; ++nf)
          acc[mf][nf] = __builtin_amdgcn_mfma_f32_16x16x32_f16(af[mf], bfr[nf], acc[mf][nf], 0, 0, 0);
    }
  }
  #pragma unroll
  for (int nf = 0; nf < 4; ++nf) {
    const int c = n0 + wn*64 + nf*16 + lr;
    const float bias = bcat1[c];
    #pragma unroll
    for (int mf = 0; mf < 4; ++mf)
      #pragma unroll
      for (int v = 0; v < 4; ++v) {
        const int r = m0 + wm*64 + mf*16 + lk*4 + v;
        E[(size_t)r*512 + c] = (_Float16)(acc[mf][nf][v] + bias);
      }
  }
}

// ---------------- fused hidden + deterministic segment-sum (1 wave/node, f16x8) ----------------
__global__ __launch_bounds__(64) void k_agg_fused(
    const _Float16* __restrict__ FT, const _Float16* __restrict__ E,
    const int* __restrict__ from_idx, const int* __restrict__ to_idx,
    const int* __restrict__ in_cnt, const int* __restrict__ in_list,
    const int* __restrict__ out_cnt, const int* __restrict__ out_list,
    _Float16* __restrict__ Hsum)
{
  const int g = blockIdx.x;
  const int b = g / NPB_;
  const int lane = threadIdx.x;
  const int half = lane >> 5;          // 0 = in, 1 = out
  const int c8 = (lane & 31) * 8;      // element offset within 256
  const int ebase = b * EPB_;
  const size_t ftg = (size_t)g * 1024;

  const f16x8 base = (half == 0) ? *(const f16x8*)&FT[ftg + 512 + c8]    // T[n]
                                 : *(const f16x8*)&FT[ftg + 256 + c8];   // F[n] (r-part)
  const int cnt = (half == 0) ? in_cnt[g] : out_cnt[g];
  const int* lst = (half == 0) ? &in_list[(size_t)g*DEGCAP_] : &out_list[(size_t)g*DEGCAP_];
  const int eoff = half * 256;
  const int foff = (half == 0) ? 0 : 768;

  float acc[8] = {};
  for (int i = 0; i < cnt; ++i) {
    const int ge = ebase + lst[i];
    const int other = (half == 0) ? from_idx[ge] : to_idx[ge];
    const f16x8 fo = *(const f16x8*)&FT[(size_t)other*1024 + foff + c8];
    const f16x8 ev = *(const f16x8*)&E[(size_t)ge*512 + eoff + c8];
    #pragma unroll
    for (int k = 0; k < 8; ++k)
      acc[k] += fmaxf((float)base[k] + (float)fo[k] + (float)ev[k], 0.f);
  }
  f16x8 o;
  #pragma unroll
  for (int k = 0; k < 8; ++k) o[k] = (_Float16)acc[k];
  *(f16x8*)&Hsum[(size_t)g*512 + eoff + c8] = o;
}

// ---------------- fused GEMM: hn = [hb | Hsum] @ WuT + ic*c1 + oc*c2 + bu ----------------
// M=9216, N=128, K=640.  BM=64 -> 144 blocks for better CU coverage.
__global__ __launch_bounds__(256) void k_gemm_upd(
    const _Float16* __restrict__ hb, const _Float16* __restrict__ Hsum,
    const _Float16* __restrict__ WuT,
    const int* __restrict__ in_cnt, const int* __restrict__ out_cnt,
    const float* __restrict__ c1, const float* __restrict__ c2,
    const float* __restrict__ bu,
    float* __restrict__ hn, _Float16* __restrict__ hbn)
{
  const int m0 = blockIdx.x * 64;
  __shared__ _Float16 As[64*64];    // 8 KB
  __shared__ _Float16 Bs[128*64];   // 16 KB
  const int tid = threadIdx.x;
  const int wave = tid >> 6, lane = tid & 63;
  const int wm = wave >> 1, wn = wave & 1;   // wm: 32-row half, wn: 64-col half
  const int lr = lane & 15, lk = lane >> 4;
  f32x4 acc[2][4] = {};
  for (int kt = 0; kt < 10; ++kt) {
    __syncthreads();
    #pragma unroll
    for (int i = 0; i < 2; ++i) {          // A: 64 rows x 8 chunks = 512 slots
      const int sidx = tid + i*256;
      const int r = sidx >> 3, sl = sidx & 7;
      const int ss = sl ^ (r & 7);
      const _Float16* asrc = (kt < 2)
          ? hb   + (size_t)(m0 + r)*128 + kt*64 + ss*8
          : Hsum + (size_t)(m0 + r)*512 + (kt - 2)*64 + ss*8;
      gload16(asrc, &As[r*64 + sl*8]);
    }
    #pragma unroll
    for (int i = 0; i < 4; ++i) {          // B: 128 n x 8 chunks = 1024 slots
      const int sidx = tid + i*256;
      const int n = sidx >> 3, sl = sidx & 7;
      const int ss = sl ^ (n & 7);
      gload16(WuT + (size_t)n*640 + kt*64 + ss*8, &Bs[n*64 + sl*8]);
    }
    __syncthreads();
    #pragma unroll
    for (int ks = 0; ks < 2; ++ks) {
      f16x8 af[2], bfr[4];
      #pragma unroll
      for (int mf = 0; mf < 2; ++mf) {
        const int r = wm*32 + mf*16 + lr;
        const int ch = (ks*4 + lk) ^ (r & 7);
        af[mf] = *(const f16x8*)&As[r*64 + ch*8];
      }
      #pragma unroll
      for (int nf = 0; nf < 4; ++nf) {
        const int n = wn*64 + nf*16 + lr;
        const int ch = (ks*4 + lk) ^ (n & 7);
        bfr[nf] = *(const f16x8*)&Bs[n*64 + ch*8];
      }
      #pragma unroll
      for (int mf = 0; mf < 2; ++mf)
        #pragma unroll
        for (int nf = 0; nf < 4; ++nf)
          acc[mf][nf] = __builtin_amdgcn_mfma_f32_16x16x32_f16(af[mf], bfr[nf], acc[mf][nf], 0, 0, 0);
    }
  }
  #pragma unroll
  for (int nf = 0; nf < 4; ++nf) {
    const int c = wn*64 + nf*16 + lr;
    const float b1 = c1[c], b2 = c2[c], b0 = bu[c];
    #pragma unroll
    for (int mf = 0; mf < 2; ++mf)
      #pragma unroll
      for (int v = 0; v < 4; ++v) {
        const int r = m0 + wm*32 + mf*16 + lk*4 + v;
        const float o = acc[mf][nf][v] + in_cnt[r]*b1 + out_cnt[r]*b2 + b0;
        hn[(size_t)r*128 + c] = o;
        hbn[(size_t)r*128 + c] = (_Float16)o;
      }
  }
}

// ---------------- node target embeddings ----------------
__global__ __launch_bounds__(128) void k_node_emb(
    const float* __restrict__ h,
    const float* __restrict__ Wq1, const float* __restrict__ bq1,
    const float* __restrict__ Wq2, const float* __restrict__ bq2,
    float* __restrict__ tq_emb, float* __restrict__ tc_emb)
{
  const int bid = blockIdx.x;
  const int b = bid / (2*NMAX_), s = bid - b*(2*NMAX_);
  const bool isQ = s < NMAX_;
  const int r = isQ ? s : s - NMAX_;
  float* outp = (isQ ? tq_emb : tc_emb) + ((size_t)b*NMAX_ + r)*TD_;
  const int tid = threadIdx.x;
  if (isQ && r >= NQ_) {
    if (tid < TD_) outp[tid] = 0.f;
    return;
  }
  const int node = b*NPB_ + (isQ ? r : NQ_ + r);
  __shared__ float xs[D_];
  __shared__ float l1[TD_];
  xs[tid] = h[(size_t)node*D_ + tid];
  __syncthreads();
  if (tid < TD_) {
    float a = bq1[tid];
    for (int k = 0; k < D_; ++k) a = fmaf(xs[k], Wq1[(size_t)k*TD_ + tid], a);
    l1[tid] = fmaxf(a, 0.f);
  }
  __syncthreads();
  if (tid < TD_) {
    float a = bq2[tid];
    #pragma unroll
    for (int k = 0; k < TD_; ++k) a = fmaf(l1[k], Wq2[(size_t)k*TD_ + tid], a);
    outp[tid] = a;
  }
}

// ---------------- sinkhorn over 40x40 node plans ----------------
__global__ __launch_bounds__(256) void k_sinkhorn_n(
    const float* __restrict__ tq_emb, const float* __restrict__ tc_emb,
    float* __restrict__ plan_n)
{
  const int b = blockIdx.x, tid = threadIdx.x;
  __shared__ float la[NMAX_][NMAX_];
  __shared__ float qe[NMAX_][TD_], ce[NMAX_][TD_];
  for (int idx = tid; idx < NMAX_*TD_; idx += 256) {
    qe[idx / TD_][idx % TD_] = tq_emb[(size_t)b*NMAX_*TD_ + idx];
    ce[idx / TD_][idx % TD_] = tc_emb[(size_t)b*NMAX_*TD_ + idx];
  }
  __syncthreads();
  for (int idx = tid; idx < NMAX_*NMAX_; idx += 256) {
    int q = idx / NMAX_, c = idx - q*NMAX_;
    float a = 0.f;
    #pragma unroll
    for (int d = 0; d < TD_; ++d) a = fmaf(qe[q][d], ce[c][d], a);
    la[q][c] = a * L2E10_;
  }
  __syncthreads();
  for (int it = 0; it < ITERS_; ++it) {
    if (tid < NMAX_) {
      float m = -INFINITY;
      for (int c = 0; c < NMAX_; ++c) m = fmaxf(m, la[tid][c]);
      float s = 0.f;
      for (int c = 0; c < NMAX_; ++c) s += ex2(la[tid][c] - m);
      const float lse = m + lg2(s);
      for (int c = 0; c < NMAX_; ++c) la[tid][c] -= lse;
    }
    __syncthreads();
    if (tid < NMAX_) {
      float m = -INFINITY;
      for (int q = 0; q < NMAX_; ++q) m = fmaxf(m, la[q][tid]);
      float s = 0.f;
      for (int q = 0; q < NMAX_; ++q) s += ex2(la[q][tid] - m);
      const float lse = m + lg2(s);
      for (int q = 0; q < NMAX_; ++q) la[q][tid] -= lse;
    }
    __syncthreads();
  }
  for (int idx = tid; idx < NMAX_*NMAX_; idx += 256)
    plan_n[(size_t)b*NMAX_*NMAX_ + idx] = ex2(la[idx / NMAX_][idx % NMAX_]);
}

// ---------------- final edge embed via MFMA ----------------
__global__ __launch_bounds__(256) void k_edge_emb_f(
    const _Float16* __restrict__ FT, const _Float16* __restrict__ E,
    const int* __restrict__ from_idx, const int* __restrict__ to_idx,
    const _Float16* __restrict__ WceTh, const float* __restrict__ bce,
    const float* __restrict__ We2, const float* __restrict__ be2,
    float* __restrict__ teq, float* __restrict__ tec)
{
  __shared__ _Float16 smem[64 * 512];   // 64 KB; wave w owns smem + w*8192
  const int tid = threadIdx.x;
  const int w = tid >> 6, lane = tid & 63;
  const int lr = lane & 15, lk = lane >> 4;
  _Float16* esw = smem + w * 8192;      // 16 rows x 512 (64 chunks x 8)
  const int e0 = blockIdx.x * 64 + w * 16;

  f16x8 bfrag[16];
  #pragma unroll
  for (int ks = 0; ks < 16; ++ks)
    bfrag[ks] = *(const f16x8*)&WceTh[(size_t)lr*512 + (size_t)(ks*4 + lk)*8];

  for (int i = 0; i < 16; ++i) {
    const int ge = e0 + i;
    const int sf = from_idx[ge], st = to_idx[ge];
    const int c8 = lane * 8;
    const f16x8 fa = *(const f16x8*)&FT[(size_t)sf*1024 + c8];
    const f16x8 fb = *(const f16x8*)&FT[(size_t)st*1024 + 512 + c8];
    const f16x8 ev = *(const f16x8*)&E[(size_t)ge*512 + c8];
    f16x8 o;
    #pragma unroll
    for (int k = 0; k < 8; ++k)
      o[k] = (_Float16)fmaxf((float)fa[k] + (float)fb[k] + (float)ev[k], 0.f);
    *(f16x8*)&esw[i*512 + ((lane ^ (i & 7)) * 8)] = o;
  }
  __syncthreads();

  f32x4 acc = {};
  #pragma unroll
  for (int ks = 0; ks < 16; ++ks) {
    const int ch = (ks*4 + lk) ^ (lr & 7);
    const f16x8 af = *(const f16x8*)&esw[lr*512 + ch*8];
    acc = __builtin_amdgcn_mfma_f32_16x16x32_f16(af, bfrag[ks], acc, 0, 0, 0);
  }
  __syncthreads();

  float* l1f = (float*)esw;
  const float bc = bce[lr];
  #pragma unroll
  for (int v = 0; v < 4; ++v)
    l1f[(lk*4 + v)*16 + lr] = fmaxf(acc[v] + bc, 0.f);
  __syncthreads();

  const float b2 = be2[lr];
  #pragma unroll
  for (int v = 0; v < 4; ++v) {
    const int e = lk*4 + v;
    float a = b2;
    #pragma unroll
    for (int k = 0; k < TD_; ++k) a = fmaf(l1f[e*16 + k], We2[(size_t)k*TD_ + lr], a);
    const int ei = e0 + e;
    const int bb = ei / EPB_, jl = ei - bb*EPB_;
    if (jl < EQ_) teq[((size_t)bb*EMAX_ + jl)*TD_ + lr] = a;
    else          tec[((size_t)bb*EMAX_ + (jl - EQ_))*TD_ + lr] = a;
  }
}

// ---------------- fused: escore + sinkhorn_e (registers, base-2, no col-max) + final score --------
// R9 formulation (no colacc/lsei persistent arrays -> no spill).
__global__ __launch_bounds__(1024) void k_plan_score(
    const float* __restrict__ teq, const float* __restrict__ tec,
    const float* __restrict__ plan_n,
    const float* __restrict__ tq_emb, const float* __restrict__ tc_emb,
    const int* __restrict__ fq, const int* __restrict__ tq,
    const int* __restrict__ fc, const int* __restrict__ tc,
    const float* __restrict__ Wa, const float* __restrict__ ba,
    float* __restrict__ out)
{
  const int b = blockIdx.x, t = threadIdx.x;
  const int tr = t >> 4, tcg = t & 15, lane = t & 63, w = t >> 6;

  __shared__ float shm[8704];    // overlay: {sq,sc} | wovs | epilogue tables
  __shared__ float bcast[256];

  {
    float* sq = shm;             // 256*17
    float* sc = shm + 4352;      // 256*17
    for (int idx = t; idx < 4096; idx += 1024) {
      const int r = idx >> 4, k = idx & 15;
      sq[r*17 + k] = teq[(size_t)b*4096 + idx];
      sc[r*17 + k] = tec[(size_t)b*4096 + idx];
    }
  }
  __syncthreads();

  float la[4][16];
  {
    const float* sq = shm;
    const float* sc = shm + 4352;
    #pragma unroll
    for (int i = 0; i < 4; ++i)
      #pragma unroll
      for (int j = 0; j < 16; ++j) la[i][j] = 0.f;
    for (int k = 0; k < 16; ++k) {
      float qk[4];
      #pragma unroll
      for (int i = 0; i < 4; ++i) qk[i] = sq[(tr*4 + i)*17 + k];
      #pragma unroll
      for (int j = 0; j < 16; ++j) {
        const float sck = sc[(j*16 + tcg)*17 + k];
        #pragma unroll
        for (int i = 0; i < 4; ++i) la[i][j] = fmaf(qk[i], sck, la[i][j]);
      }
    }
    #pragma unroll
    for (int i = 0; i < 4; ++i)
      #pragma unroll
      for (int j = 0; j < 16; ++j) la[i][j] *= L2E10_;
  }
  __syncthreads();   // sq/sc dead; shm reused as wovs

  float* wovs = shm;           // 4096

  for (int it = 0; it < ITERS_; ++it) {
    // ---- row LSE (16 consecutive lanes per row); tree reductions ----
    #pragma unroll
    for (int i = 0; i < 4; ++i) {
      float m = fmaxf(
        fmaxf(fmaxf(fmaxf(la[i][0],la[i][1]), fmaxf(la[i][2],la[i][3])),
              fmaxf(fmaxf(la[i][4],la[i][5]), fmaxf(la[i][6],la[i][7]))),
        fmaxf(fmaxf(fmaxf(la[i][8],la[i][9]), fmaxf(la[i][10],la[i][11])),
              fmaxf(fmaxf(la[i][12],la[i][13]), fmaxf(la[i][14],la[i][15]))));
      m = fmaxf(m, __shfl_xor(m, 1)); m = fmaxf(m, __shfl_xor(m, 2));
      m = fmaxf(m, __shfl_xor(m, 4)); m = fmaxf(m, __shfl_xor(m, 8));
      float p[16];
      #pragma unroll
      for (int j = 0; j < 16; ++j) p[j] = ex2(la[i][j] - m);
      float s = (((p[0]+p[1]) + (p[2]+p[3])) + ((p[4]+p[5]) + (p[6]+p[7])))
              + (((p[8]+p[9]) + (p[10]+p[11])) + ((p[12]+p[13]) + (p[14]+p[15])));
      s += __shfl_xor(s, 1); s += __shfl_xor(s, 2);
      s += __shfl_xor(s, 4); s += __shfl_xor(s, 8);
      const float lse = m + lg2(s);
      #pragma unroll
      for (int j = 0; j < 16; ++j) la[i][j] -= lse;
    }
    // ---- col sums: la <= 0 after row norm -> no max needed ----
    #pragma unroll
    for (int j = 0; j < 16; ++j) {
      float s = (ex2(la[0][j]) + ex2(la[1][j])) + (ex2(la[2][j]) + ex2(la[3][j]));
      s += __shfl_xor(s, 16);
      s += __shfl_xor(s, 32);
      if (lane < 16) wovs[w*256 + j*16 + lane] = s;
    }
    __syncthreads();
    if (t < 256) {
      float s0 = 0.f, s1 = 0.f, s2 = 0.f, s3 = 0.f;
      #pragma unroll
      for (int ww = 0; ww < 16; ww += 4) {
        s0 += wovs[(ww+0)*256 + t];
        s1 += wovs[(ww+1)*256 + t];
        s2 += wovs[(ww+2)*256 + t];
        s3 += wovs[(ww+3)*256 + t];
      }
      bcast[t] = lg2(fmaxf((s0 + s1) + (s2 + s3), 1e-30f));
    }
    __syncthreads();
    #pragma unroll
    for (int j = 0; j < 16; ++j) {
      const float lse = bcast[j*16 + tcg];
      #pragma unroll
      for (int i = 0; i < 4; ++i) la[i][j] -= lse;
    }
  }
  __syncthreads();

  // ---- epilogue: overlay pn/qe/ce/indices into shm ----
  float* pn = shm;                 // 1600
  float* qe = shm + 1600;          // 640
  float* ce = shm + 2240;          // 640
  int*   ib = (int*)(shm + 2880);  // 800 ints
  int* sfq = ib, *stq = ib + 160, *sfc = ib + 320, *stc = ib + 560;
  for (int i = t; i < 1600; i += 1024) pn[i] = plan_n[(size_t)b*1600 + i];
  if (t < 640) { qe[t] = tq_emb[(size_t)b*640 + t]; ce[t] = tc_emb[(size_t)b*640 + t]; }
  if (t < 160) { sfq[t] = fq[b*160 + t]; stq[t] = tq[b*160 + t]; }
  if (t >= 512 && t < 752) { sfc[t-512] = fc[b*240 + (t-512)]; stc[t-512] = tc[b*240 + (t-512)]; }
  __syncthreads();

  float csum = 0.f;
  if (tr < 40) {
    #pragma unroll
    for (int i = 0; i < 4; ++i) {
      const int q = tr*4 + i;
      const int g0 = sfq[q]*NMAX_, g1 = stq[q]*NMAX_;
      #pragma unroll
      for (int j = 0; j < 15; ++j) {
        const int c = j*16 + tcg;
        const float pe = ex2(la[i][j]);
        const float a0 = pn[g0 + sfc[c]] * pn[g1 + stc[c]];
        const float a1 = pn[g0 + stc[c]] * pn[g1 + sfc[c]];
        csum += pe * fmaxf(a0, a1);
      }
    }
  }
  float hsum = 0.f;
  if (t < NMAX_*TD_) {
    const int q = t >> 4, d2 = t & 15;
    float a = 0.f;
    for (int c = 0; c < NMAX_; ++c) a = fmaf(pn[q*NMAX_ + c], ce[c*TD_ + d2], a);
    hsum = fmaxf(qe[t] - a, 0.f);
  }
  #pragma unroll
  for (int off = 32; off; off >>= 1) {
    csum += __shfl_xor(csum, off);
    hsum += __shfl_xor(hsum, off);
  }
  if (lane == 0) { bcast[w] = csum; bcast[32 + w] = hsum; }
  __syncthreads();
  if (t == 0) {
    float C = 0.f, H = 0.f;
    #pragma unroll
    for (int ww = 0; ww < 16; ++ww) { C += bcast[ww]; H += bcast[32 + ww]; }
    out[b] = (-H) * Wa[0] + C * Wa[1] + ba[0];
  }
}

// ---------------- host launcher ----------------
extern "C" void kernel_launch(void* const* d_in, const int* in_sizes, int n_in,
                              void* d_out, int out_size, void* d_ws, size_t ws_size,
                              hipStream_t stream) {
  const float* node_features = (const float*)d_in[0];
  const float* edge_features = (const float*)d_in[1];
  const float* Wn  = (const float*)d_in[2];
  const float* bn  = (const float*)d_in[3];
  const float* We  = (const float*)d_in[4];
  const float* be  = (const float*)d_in[5];
  const float* Wm1 = (const float*)d_in[6];
  const float* bm1 = (const float*)d_in[7];
  const float* Wm2 = (const float*)d_in[8];
  const float* bm2 = (const float*)d_in[9];
  const float* Wr1 = (const float*)d_in[10];
  const float* br1 = (const float*)d_in[11];
  const float* Wr2 = (const float*)d_in[12];
  const float* br2 = (const float*)d_in[13];
  const float* Wu  = (const float*)d_in[14];
  const float* bu  = (const float*)d_in[15];
  const float* Wq1 = (const float*)d_in[16];
  const float* bq1 = (const float*)d_in[17];
  const float* Wq2 = (const float*)d_in[18];
  const float* bq2 = (const float*)d_in[19];
  const float* We1 = (const float*)d_in[20];
  const float* be1 = (const float*)d_in[21];
  const float* We2 = (const float*)d_in[22];
  const float* be2 = (const float*)d_in[23];
  const float* Wa  = (const float*)d_in[24];
  const float* ba  = (const float*)d_in[25];
  const int* fq = (const int*)d_in[26];
  const int* tq = (const int*)d_in[27];
  const int* fc = (const int*)d_in[28];
  const int* tc = (const int*)d_in[29];
  (void)in_sizes; (void)n_in; (void)out_size; (void)ws_size;

  char* ws = (char*)d_ws;
  size_t off = 0;
  auto take = [&](size_t bytes) -> void* {
    void* p = ws + off;
    off = (off + bytes + 255) & ~(size_t)255;
    return p;
  };
  int*   from_idx = (int*)  take((size_t)ETOT_*4);
  int*   to_idx   = (int*)  take((size_t)ETOT_*4);
  int*   in_cnt   = (int*)  take((size_t)NTOT_*4);
  int*   out_cnt  = (int*)  take((size_t)NTOT_*4);
  int*   in_list  = (int*)  take((size_t)NTOT_*DEGCAP_*4);
  int*   out_list = (int*)  take((size_t)NTOT_*DEGCAP_*4);
  float* h0       = (float*)take((size_t)NTOT_*D_*4);
  float* h1       = (float*)take((size_t)NTOT_*D_*4);
  _Float16* hbA   = (_Float16*)take((size_t)NTOT_*D_*2);
  _Float16* hbB   = (_Float16*)take((size_t)NTOT_*D_*2);
  _Float16* eb    = (_Float16*)take((size_t)ETOT_*D_*2);
  _Float16* FT    = (_Float16*)take((size_t)NTOT_*1024*2);
  _Float16* Ebuf  = (_Float16*)take((size_t)ETOT_*512*2);
  _Float16* Hsum  = (_Float16*)take((size_t)NTOT_*512*2);
  float* tq_emb   = (float*)take((size_t)B_*NMAX_*TD_*4);
  float* tc_emb   = (float*)take((size_t)B_*NMAX_*TD_*4);
  float* plan_n   = (float*)take((size_t)B_*NMAX_*NMAX_*4);
  float* teq      = (float*)take((size_t)B_*EMAX_*TD_*4);
  float* tec      = (float*)take((size_t)B_*EMAX_*TD_*4);
  _Float16* W1Tn  = (_Float16*)take((size_t)1024*128*2);
  _Float16* W1Te  = (_Float16*)take((size_t)512*128*2);
  _Float16* WuT   = (_Float16*)take((size_t)128*640*2);
  float* bcat1    = (float*)take(512*4);
  float* c1       = (float*)take(128*4);
  float* c2       = (float*)take(128*4);
  _Float16* WceTh = (_Float16*)take((size_t)16*512*2);
  float* bce      = (float*)take(16*4);

  k_build_idx<<<(ETOT_ + 255)/256, 256, 0, stream>>>(fq, tq, fc, tc, from_idx, to_idx);
  k_build_lists<<<B_, 256, 0, stream>>>(fq, tq, fc, tc, in_cnt, in_list, out_cnt, out_list);
  k_prep_w<<<(1024*128 + 512*128)/256, 256, 0, stream>>>(
      Wm1, Wr1, bm1, br1, W1Tn, W1Te, bcat1);
  k_prep_wu<<<(128*640 + 255)/256, 256, 0, stream>>>(Wm2, Wr2, Wu, bm2, br2, WuT, c1, c2);
  k_prep_wce<<<32, 256, 0, stream>>>(Wm2, Wr2, We1, bm2, br2, be1, WceTh, bce);
  k_node_enc<<<NTOT_, D_, 0, stream>>>(node_features, Wn, bn, h0, hbA);
  k_edge_enc<<<ETOT_, D_, 0, stream>>>(edge_features, We, be, eb);

  dim3 gE(ETOT_/128, 4);
  k_gemm_E<<<gE, 256, 0, stream>>>(eb, W1Te, bcat1, Ebuf);

  dim3 gFT(NTOT_/128, 8);
  float* hc = h0;  float* hn = h1;
  _Float16* hbc = hbA;  _Float16* hbn = hbB;
  for (int p = 0; p < NPROP_; ++p) {
    k_gemm_FT<<<gFT, 256, 0, stream>>>(hbc, W1Tn, FT);
    k_agg_fused<<<NTOT_, 64, 0, stream>>>(FT, Ebuf, from_idx, to_idx,
                                          in_cnt, in_list, out_cnt, out_list, Hsum);
    k_gemm_upd<<<NTOT_/64, 256, 0, stream>>>(hbc, Hsum, WuT, in_cnt, out_cnt,
                                             c1, c2, bu, hn, hbn);
    float* tf = hc; hc = hn; hn = tf;
    _Float16* th = hbc; hbc = hbn; hbn = th;
  }

  k_node_emb<<<B_*2*NMAX_, D_, 0, stream>>>(hc, Wq1, bq1, Wq2, bq2, tq_emb, tc_emb);
  k_sinkhorn_n<<<B_, 256, 0, stream>>>(tq_emb, tc_emb, plan_n);

  k_gemm_FT<<<gFT, 256, 0, stream>>>(hbc, W1Tn, FT);
  hipMemsetAsync(teq, 0, (size_t)B_*EMAX_*TD_*4, stream);
  hipMemsetAsync(tec, 0, (size_t)B_*EMAX_*TD_*4, stream);
  k_edge_emb_f<<<ETOT_/64, 256, 0, stream>>>(FT, Ebuf, from_idx, to_idx,
                                             WceTh, bce, We2, be2, teq, tec);

  k_plan_score<<<B_, 1024, 0, stream>>>(teq, tec, plan_n, tq_emb, tc_emb,
                                        fq, tq, fc, tc, Wa, ba, (float*)d_out);
}